// Round 4
// baseline (267.910 us; speedup 1.0000x reference)
//
#include <hip/hip_runtime.h>
#include <cmath>

#define IN_CH 128
#define OUT_CH 128
#define KDIM 512           // Z row: x(128) | sum(128) | mean(128) | max(128)
#define NGEMM 384          // W^T rows: permuted (colgroup, wavehalf, section, ocol16)
#define GBM 256            // fallback gemm rows per block
#define GBM2 128           // pipe2 gemm rows per block (8-wave)
#define GBN 192            // gemm cols (W^T rows) per block
#define SLOT_B 40960       // fallback slot bytes: Ahi 16K | Bhi 12K | Blo 12K
#define SLOT_US 20480
#define SLOT2_B 32768      // pipe2 slot: A 8K | Bhi 12K | Blo 12K
#define SLOT2_US 16384
#define PIPE2_LDS_BYTES (2 * SLOT2_B)   // 64 KB -> 2 blocks/CU (2 barrier domains)

typedef __attribute__((ext_vector_type(8))) short bfrag;   // 8 bf16 in 4 VGPRs
typedef __attribute__((ext_vector_type(4))) float f32x4;

// float -> bf16 round-to-nearest-even (bit pattern)
__device__ __forceinline__ unsigned short f2bf(float f) {
    unsigned int u = __float_as_uint(f);
    return (unsigned short)((u + 0x7FFFu + ((u >> 16) & 1u)) >> 16);
}
__device__ __forceinline__ float bf2f(unsigned short h) {
    return __uint_as_float(((unsigned int)h) << 16);
}
__device__ __forceinline__ float4 unpack4(uint2 u) {
    float4 r;
    r.x = __uint_as_float(u.x << 16);
    r.y = __uint_as_float(u.x & 0xFFFF0000u);
    r.z = __uint_as_float(u.y << 16);
    r.w = __uint_as_float(u.y & 0xFFFF0000u);
    return r;
}

// async 16B global->LDS (wave-level; LDS side is lane-linear base+lane*16)
__device__ __forceinline__ void gl2lds16(const void* g, void* l) {
    __builtin_amdgcn_global_load_lds(
        (const __attribute__((address_space(1))) unsigned int*)g,
        (__attribute__((address_space(3))) unsigned int*)l, 16, 0, 0);
}

// ---------------- CSR build ----------------

__global__ void degree_kernel(const int* __restrict__ ei, int* __restrict__ degree, int E) {
    int e = blockIdx.x * blockDim.x + threadIdx.x;
    if (e < E) atomicAdd(&degree[ei[E + e]], 1);
}

// ---------- device-wide exclusive scan, 3 phases ----------
__global__ __launch_bounds__(256) void scan1_kernel(const int* __restrict__ degree,
                                                    int* __restrict__ part,
                                                    float* __restrict__ partlog, int n) {
    int i = blockIdx.x * 256 + threadIdx.x;
    int d = (i < n) ? degree[i] : 0;
    float lg = (i < n) ? logf((float)d + 2.0f) : 0.f;   // == log1p(d+1)
    #pragma unroll
    for (int off = 32; off; off >>= 1) {
        d += __shfl_down(d, off);
        lg += __shfl_down(lg, off);
    }
    __shared__ int sd[4];
    __shared__ float sl[4];
    int wv = threadIdx.x >> 6;
    if ((threadIdx.x & 63) == 0) { sd[wv] = d; sl[wv] = lg; }
    __syncthreads();
    if (threadIdx.x == 0) {
        part[blockIdx.x] = (sd[0] + sd[1]) + (sd[2] + sd[3]);
        partlog[blockIdx.x] = (sl[0] + sl[1]) + (sl[2] + sl[3]);
    }
}

__global__ __launch_bounds__(256) void scan2_kernel(int* __restrict__ part,
                                                    const float* __restrict__ partlog,
                                                    float* __restrict__ logsum, int B) {
    int tid = threadIdx.x, lane = tid & 63, wv = tid >> 6;
    __shared__ int wsum[4];
    __shared__ float wl[4];
    __shared__ int carry_s;
    if (tid == 0) carry_s = 0;
    float lg = 0.f;
    __syncthreads();
    for (int base0 = 0; base0 < B; base0 += 256) {
        int idx = base0 + tid;
        int v = (idx < B) ? part[idx] : 0;
        if (idx < B) lg += partlog[idx];
        int s = v;
        #pragma unroll
        for (int off = 1; off < 64; off <<= 1) {
            int t = __shfl_up(s, off);
            if (lane >= off) s += t;
        }
        if (lane == 63) wsum[wv] = s;
        __syncthreads();
        int wbase = carry_s;
        for (int w2 = 0; w2 < wv; ++w2) wbase += wsum[w2];
        if (idx < B) part[idx] = wbase + s - v;       // exclusive prefix of block sums
        __syncthreads();
        if (tid == 0) carry_s += (wsum[0] + wsum[1]) + (wsum[2] + wsum[3]);
        __syncthreads();
    }
    #pragma unroll
    for (int off = 32; off; off >>= 1) lg += __shfl_down(lg, off);
    if (lane == 0) wl[wv] = lg;
    __syncthreads();
    if (tid == 0) logsum[0] = (wl[0] + wl[1]) + (wl[2] + wl[3]);
}

__global__ __launch_bounds__(256) void scan3_kernel(const int* __restrict__ degree,
                                                    const int* __restrict__ part,
                                                    int* __restrict__ offsets, int n, int E) {
    int i = blockIdx.x * 256 + threadIdx.x;
    int d = (i < n) ? degree[i] : 0;
    int lane = threadIdx.x & 63, wv = threadIdx.x >> 6;
    int s = d;
    #pragma unroll
    for (int off = 1; off < 64; off <<= 1) {
        int t = __shfl_up(s, off);
        if (lane >= off) s += t;
    }
    __shared__ int wsum[4];
    if (lane == 63) wsum[wv] = s;
    __syncthreads();
    int base = part[blockIdx.x];
    for (int w2 = 0; w2 < wv; ++w2) base += wsum[w2];
    if (i < n) offsets[i] = base + s - d;             // exclusive prefix
    if (i == n - 1) offsets[n] = E;                   // Σ degree == E
}

// fill bumps offsets[] in place; afterwards offsets[v] == end of v's segment.
__global__ void fill_kernel(const int* __restrict__ ei, int* __restrict__ offsets,
                            int* __restrict__ csr_src, int E) {
    int e = blockIdx.x * blockDim.x + threadIdx.x;
    if (e < E) {
        int src = ei[e];
        int dst = ei[E + e];
        int pos = atomicAdd(&offsets[dst], 1);
        csr_src[pos] = src;
    }
}

// ---------------- x -> bf16 cast (halves agg gather bytes) ----------------

__global__ void xcast_kernel(const float* __restrict__ x, unsigned short* __restrict__ xb,
                             int total4) {
    int i = blockIdx.x * 256 + threadIdx.x;    // 4 elements each
    if (i >= total4) return;
    float4 v = ((const float4*)x)[i];
    uint2 p;
    p.x = (unsigned)f2bf(v.x) | ((unsigned)f2bf(v.y) << 16);
    p.y = (unsigned)f2bf(v.z) | ((unsigned)f2bf(v.w) << 16);
    ((uint2*)xb)[i] = p;
}

// ---------------- Aggregation: one WAVE per node, bf16 edge-pair gathers ---------

__global__ __launch_bounds__(256) void agg_kernel(const unsigned short* __restrict__ xb,
                                                  const int* __restrict__ csr_src,
                                                  const int* __restrict__ offsets,
                                                  const int* __restrict__ degree,
                                                  const float* __restrict__ logsum,
                                                  unsigned short* __restrict__ Zhi,
                                                  float* __restrict__ ampv,
                                                  float* __restrict__ attv,
                                                  int N, int Mpad) {
    int node = (blockIdx.x * 256 + threadIdx.x) >> 6;
    int lane = threadIdx.x & 63;
    if (node >= Mpad) return;
    int h = lane >> 5;
    int c4 = lane & 31;
    long zbase = (long)node * KDIM + c4 * 4;
    if (node >= N) {   // pad rows: zero so GEMM reads are harmless
        if (h == 0) {
            uint2 z = make_uint2(0u, 0u);
            #pragma unroll
            for (int sec = 0; sec < 4; ++sec) *(uint2*)&Zhi[zbase + sec * 128] = z;
        }
        return;
    }
    int deg = degree[node];
    int end = offsets[node];          // post-fill end of segment
    int beg = end - deg;
    const float NEG = -3.402823466e38f;
    float4 s[4], m[4];
    #pragma unroll
    for (int u = 0; u < 4; ++u) {
        s[u] = make_float4(0.f, 0.f, 0.f, 0.f);
        m[u] = make_float4(NEG, NEG, NEG, NEG);
    }
    int i = beg;
    for (; i + 8 <= end; i += 8) {      // 4 pair-slots = 8 edges, 4 indep chains
        int idx[4];
        #pragma unroll
        for (int u = 0; u < 4; ++u) idx[u] = csr_src[i + u * 2 + h];
        uint2 raw[4];
        #pragma unroll
        for (int u = 0; u < 4; ++u) raw[u] = *(const uint2*)&xb[(long)idx[u] * IN_CH + c4 * 4];
        #pragma unroll
        for (int u = 0; u < 4; ++u) {
            float4 v = unpack4(raw[u]);
            s[u].x += v.x; s[u].y += v.y; s[u].z += v.z; s[u].w += v.w;
            m[u].x = fmaxf(m[u].x, v.x); m[u].y = fmaxf(m[u].y, v.y);
            m[u].z = fmaxf(m[u].z, v.z); m[u].w = fmaxf(m[u].w, v.w);
        }
    }
    for (; i < end; i += 2) {           // tail pairs (upper half may be inactive)
        int e = i + h;
        if (e < end) {
            float4 v = unpack4(*(const uint2*)&xb[(long)csr_src[e] * IN_CH + c4 * 4]);
            s[0].x += v.x; s[0].y += v.y; s[0].z += v.z; s[0].w += v.w;
            m[0].x = fmaxf(m[0].x, v.x); m[0].y = fmaxf(m[0].y, v.y);
            m[0].z = fmaxf(m[0].z, v.z); m[0].w = fmaxf(m[0].w, v.w);
        }
    }
    float4 sum, mx;
    sum.x = (s[0].x + s[1].x) + (s[2].x + s[3].x);
    sum.y = (s[0].y + s[1].y) + (s[2].y + s[3].y);
    sum.z = (s[0].z + s[1].z) + (s[2].z + s[3].z);
    sum.w = (s[0].w + s[1].w) + (s[2].w + s[3].w);
    mx.x = fmaxf(fmaxf(m[0].x, m[1].x), fmaxf(m[2].x, m[3].x));
    mx.y = fmaxf(fmaxf(m[0].y, m[1].y), fmaxf(m[2].y, m[3].y));
    mx.z = fmaxf(fmaxf(m[0].z, m[1].z), fmaxf(m[2].z, m[3].z));
    mx.w = fmaxf(fmaxf(m[0].w, m[1].w), fmaxf(m[2].w, m[3].w));
    // cross-half combine
    sum.x += __shfl_xor(sum.x, 32); sum.y += __shfl_xor(sum.y, 32);
    sum.z += __shfl_xor(sum.z, 32); sum.w += __shfl_xor(sum.w, 32);
    mx.x = fmaxf(mx.x, __shfl_xor(mx.x, 32)); mx.y = fmaxf(mx.y, __shfl_xor(mx.y, 32));
    mx.z = fmaxf(mx.z, __shfl_xor(mx.z, 32)); mx.w = fmaxf(mx.w, __shfl_xor(mx.w, 32));

    float inv = 1.0f / fmaxf((float)deg, 1.0f);
    float4 mean = make_float4(sum.x * inv, sum.y * inv, sum.z * inv, sum.w * inv);
    if (deg == 0) mx = make_float4(0.f, 0.f, 0.f, 0.f);
    float4 xv = unpack4(*(const uint2*)&xb[(long)node * IN_CH + c4 * 4]);

    if (h == 0) {
        float4 secs[4] = { xv, sum, mean, mx };
        #pragma unroll
        for (int sec = 0; sec < 4; ++sec) {
            float4 v = secs[sec];
            uint2 hi;
            hi.x = (unsigned)f2bf(v.x) | ((unsigned)f2bf(v.y) << 16);
            hi.y = (unsigned)f2bf(v.z) | ((unsigned)f2bf(v.w) << 16);
            *(uint2*)&Zhi[zbase + sec * 128] = hi;
        }
    }
    if (lane == 0) {
        float ref = fmaxf(logsum[0] / (float)N, 1.0f);
        float dt = log1pf((float)deg + 1.0f);
        ampv[node] = dt / ref;
        attv[node] = ref / fmaxf(dt, 1e-6f);
    }
}

// ---------------- Weight build: permuted row-major W^T, bf16 hi/lo -----------------

__global__ void wbuild_kernel(const float* __restrict__ Wmsg, const float* __restrict__ Wroot,
                              unsigned short* __restrict__ Whi, unsigned short* __restrict__ Wlo) {
    int idx = blockIdx.x * 256 + threadIdx.x;
    if (idx >= NGEMM * KDIM) return;
    int jp = idx >> 9;       // 0..383
    int k = idx & 511;
    int cg = jp / 96;
    int rem = jp - cg * 96;
    int s16 = rem >> 4;
    int r16 = rem & 15;
    int wn2 = s16 / 3;
    int sec = s16 - wn2 * 3;
    int ocol = cg * 32 + wn2 * 16 + r16;
    float v;
    if (k < 128) {
        v = (sec == 0) ? Wroot[ocol * 128 + k] : 0.f;
    } else {
        int a = (k - 128) >> 7;
        int c = (k - 128) & 127;
        v = Wmsg[ocol * 1152 + (a * 3 + sec) * 128 + c];
    }
    unsigned short h = f2bf(v);
    Whi[idx] = h;
    Wlo[idx] = f2bf(v - bf2f(h));
}

// ---------------- MFMA GEMM: 8-wave blocks, D=2 ring, 2 blocks/CU ------------------
// Theory (r4): per-iter cost was barrier-convergence dead time in one 16-wave
// domain/CU. Two independent 8-wave blocks per CU (64 KB LDS each) let one
// block's MFMA/ds_read phase fill the other's drain/barrier phase.
// Per wave/stage: 4 gl2lds16 (1 A + 3 B), uniform. Slot: A 8K | Bhi 12K | Blo 12K.
// Per iter: fire stage it+1 -> other slot; read slot it&1; 24 MFMA; vmcnt(0);
// raw s_barrier (no compiler drain). Per-wave tile/work identical to r2/r3 kernel.

__global__ __launch_bounds__(512, 4) void gemm_pipe2(const unsigned short* __restrict__ Zhi,
                                                     const unsigned short* __restrict__ Whi,
                                                     const unsigned short* __restrict__ Wlo,
                                                     const float* __restrict__ ampv,
                                                     const float* __restrict__ attv,
                                                     const float* __restrict__ bmsg,
                                                     const float* __restrict__ broot,
                                                     float* __restrict__ out, int M) {
    extern __shared__ char smem[];
    unsigned short* lds = (unsigned short*)smem;
    const int tid = threadIdx.x;            // 0..511
    const int w = tid >> 6;                 // 0..7
    const int lane = tid & 63;
    const int r16 = lane & 15, q = lane >> 4;
    const int wm = w >> 2, wn = w & 3;      // wm 0..1, wn 0..3
    const int row0 = blockIdx.x * GBM2;
    const int cg2 = blockIdx.y;             // 0..1

    // A: rows row0 + w*16 + r16; B: 3 loads b = w*3+j over 24 x 1KB (hi 0..11, lo 12..23)
    const unsigned short* sA = Zhi + (long)(row0 + w * 16 + r16) * KDIM + q * 8;
    const unsigned short* sB0;
    const unsigned short* sB1;
    const unsigned short* sB2;
    {
        int b0 = w * 3;
        const unsigned short* p[3];
        #pragma unroll
        for (int j = 0; j < 3; ++j) {
            int b = b0 + j;
            const unsigned short* Wb = (b < 12) ? Whi : Wlo;
            int rrow = ((b < 12) ? b : (b - 12)) * 16;
            p[j] = Wb + (long)(cg2 * GBN + rrow + r16) * KDIM + q * 8;
        }
        sB0 = p[0]; sB1 = p[1]; sB2 = p[2];
    }
    const int dA = tid * 16;                                  // A region [0, 8192)
    const int dB0 = 8192 + (w * 3 + 0) * 1024 + lane * 16;    // B region [8192, 32768)
    const int dB1 = 8192 + (w * 3 + 1) * 1024 + lane * 16;
    const int dB2 = 8192 + (w * 3 + 2) * 1024 + lane * 16;

    // prologue: stage 0 -> slot 0
    gl2lds16(sA, smem + dA); gl2lds16(sB0, smem + dB0);
    gl2lds16(sB1, smem + dB1); gl2lds16(sB2, smem + dB2);
    sA += 32; sB0 += 32; sB1 += 32; sB2 += 32;
    __builtin_amdgcn_s_waitcnt(0x0F70);      // vmcnt(0): stage 0 landed
    __builtin_amdgcn_s_barrier();
    __builtin_amdgcn_sched_barrier(0);

    f32x4 acc[4][3] = {};
    const int jtb = (wn >> 1) * 6 + (wn & 1) * 3;

    #pragma unroll 1
    for (int it = 0; it < 16; ++it) {
        const int s = it & 1;
        if (it + 1 < 16) {                   // fire stage it+1 -> other slot
            char* b = smem + (s ^ 1) * SLOT2_B;
            gl2lds16(sA, b + dA); gl2lds16(sB0, b + dB0);
            gl2lds16(sB1, b + dB1); gl2lds16(sB2, b + dB2);
            sA += 32; sB0 += 32; sB1 += 32; sB2 += 32;
        }
        const unsigned short* L = lds + s * SLOT2_US;

        bfrag bh[3], bl[3];
        #pragma unroll
        for (int nt = 0; nt < 3; ++nt) {
            int chb = (jtb + nt) * 512 + lane * 8;
            bh[nt] = *(const bfrag*)&L[4096 + chb];     // Bhi at us 4096
            bl[nt] = *(const bfrag*)&L[10240 + chb];    // Blo at us 10240
        }
        #pragma unroll
        for (int mt = 0; mt < 4; ++mt) {
            bfrag ah = *(const bfrag*)&L[((wm * 4 + mt) * 64 + lane) * 8];
            #pragma unroll
            for (int nt = 0; nt < 3; ++nt) {
                acc[mt][nt] = __builtin_amdgcn_mfma_f32_16x16x32_bf16(ah, bh[nt], acc[mt][nt], 0, 0, 0);
                acc[mt][nt] = __builtin_amdgcn_mfma_f32_16x16x32_bf16(ah, bl[nt], acc[mt][nt], 0, 0, 0);
            }
        }

        if (it + 1 < 16) __builtin_amdgcn_s_waitcnt(0x0F70);   // stage it+1 landed
        if (it < 15) {
            __builtin_amdgcn_s_barrier();    // slot consumed + next stage ready
            __builtin_amdgcn_sched_barrier(0);
        }
    }

    // fused epilogue: C/D layout col=lane&15, row=q*4+r (verified m89/m91)
    const int col = (cg2 * 2 + (wn >> 1)) * 32 + (wn & 1) * 16 + r16;
    const float bias = bmsg[col] + broot[col];
    #pragma unroll
    for (int mt = 0; mt < 4; ++mt) {
        #pragma unroll
        for (int r = 0; r < 4; ++r) {
            int row = row0 + wm * 64 + mt * 16 + q * 4 + r;
            if (row < M) {
                float v = acc[mt][0][r]
                        + ampv[row] * acc[mt][1][r]
                        + attv[row] * acc[mt][2][r] + bias;
                out[(long)row * OUT_CH + col] = v;
            }
        }
    }
}

// ---------------- fallback: single-buffer (static 40 KB), 16-wave, barriers --------

__global__ __launch_bounds__(1024, 4) void gemm_sb(const unsigned short* __restrict__ Zhi,
                                                   const unsigned short* __restrict__ Whi,
                                                   const unsigned short* __restrict__ Wlo,
                                                   const float* __restrict__ ampv,
                                                   const float* __restrict__ attv,
                                                   const float* __restrict__ bmsg,
                                                   const float* __restrict__ broot,
                                                   float* __restrict__ out, int M) {
    __shared__ unsigned short lds[SLOT_US];   // 40 KB
    const int tid = threadIdx.x;
    const int w = tid >> 6;
    const int lane = tid & 63;
    const int r16 = lane & 15, q = lane >> 4;
    const int wm = w >> 2, wn = w & 3;
    const int row0 = blockIdx.x * GBM;
    const int cg2 = blockIdx.y;

    const unsigned short* sAh = Zhi + (long)(row0 + w * 16 + r16) * KDIM + q * 8;
    const unsigned short* sB2 = (w < 12)
        ? Whi + (long)(cg2 * GBN + w * 16 + r16) * KDIM + q * 8
        : Wlo + (long)(cg2 * GBN + (w - 12) * 16 + r16) * KDIM + q * 8;
    const unsigned short* sB3 = Wlo + (long)(cg2 * GBN + (4 + w) * 16 + r16) * KDIM + q * 8;
    char* ldsb = (char*)lds;
    const int d0 = tid * 16, d2 = (1024 + tid) * 16, d3 = (2048 + tid) * 16;

    f32x4 acc[4][3] = {};
    const int jtb = (wn >> 1) * 6 + (wn & 1) * 3;

    #pragma unroll 1
    for (int it = 0; it < 16; ++it) {
        if (it) __syncthreads();
        gl2lds16(sAh, ldsb + d0); gl2lds16(sB2, ldsb + d2); if (w < 8) gl2lds16(sB3, ldsb + d3);
        sAh += 32; sB2 += 32; sB3 += 32;
        __syncthreads();

        bfrag bh[3], bl[3];
        #pragma unroll
        for (int nt = 0; nt < 3; ++nt) {
            int chb = (jtb + nt) * 512 + lane * 8;
            bh[nt] = *(const bfrag*)&lds[8192 + chb];
            bl[nt] = *(const bfrag*)&lds[14336 + chb];
        }
        #pragma unroll
        for (int mt = 0; mt < 4; ++mt) {
            bfrag ah = *(const bfrag*)&lds[((wm * 4 + mt) * 64 + lane) * 8];
            #pragma unroll
            for (int nt = 0; nt < 3; ++nt) {
                acc[mt][nt] = __builtin_amdgcn_mfma_f32_16x16x32_bf16(ah, bh[nt], acc[mt][nt], 0, 0, 0);
                acc[mt][nt] = __builtin_amdgcn_mfma_f32_16x16x32_bf16(ah, bl[nt], acc[mt][nt], 0, 0, 0);
            }
        }
    }

    const int col = (cg2 * 2 + (wn >> 1)) * 32 + (wn & 1) * 16 + r16;
    const float bias = bmsg[col] + broot[col];
    #pragma unroll
    for (int mt = 0; mt < 4; ++mt) {
        #pragma unroll
        for (int r = 0; r < 4; ++r) {
            int row = row0 + wm * 64 + mt * 16 + q * 4 + r;
            if (row < M) {
                float v = acc[mt][0][r]
                        + ampv[row] * acc[mt][1][r]
                        + attv[row] * acc[mt][2][r] + bias;
                out[(long)row * OUT_CH + col] = v;
            }
        }
    }
}

// ---------------- Launch ----------------

extern "C" void kernel_launch(void* const* d_in, const int* in_sizes, int n_in,
                              void* d_out, int out_size, void* d_ws, size_t ws_size,
                              hipStream_t stream) {
    const float* x     = (const float*)d_in[0];
    const int*   ei    = (const int*)d_in[1];
    const float* Wmsg  = (const float*)d_in[2];
    const float* bmsg  = (const float*)d_in[3];
    const float* Wroot = (const float*)d_in[4];
    const float* broot = (const float*)d_in[5];
    float* out = (float*)d_out;

    int N = in_sizes[0] / IN_CH;           // 50000
    int E = in_sizes[1] / 2;               // 600000
    int Mb = (N + GBM - 1) / GBM;          // 196 (fallback grid + Zhi padding)
    int Mpad = Mb * GBM;                   // 50176
    int Mb2 = (N + GBM2 - 1) / GBM2;       // 391 (pipe2 grid; 391*128 <= Mpad)
    int Sb = (N + 255) / 256;              // scan blocks (196)

    char* ws = (char*)d_ws;
    size_t off = 0;
    auto alloc = [&](size_t bytes) -> void* {
        void* p = ws + off;
        off = (off + bytes + 255) & ~(size_t)255;
        return p;
    };
    int* degree  = (int*)alloc((size_t)N * 4);
    int* offsets = (int*)alloc((size_t)(N + 1) * 4);
    float* logsum = (float*)alloc(4);
    int* part    = (int*)alloc((size_t)Sb * 4);
    float* partlog = (float*)alloc((size_t)Sb * 4);
    int* csr_src = (int*)alloc((size_t)E * 4);
    unsigned short* Whi = (unsigned short*)alloc((size_t)NGEMM * KDIM * 2);
    unsigned short* Wlo = (unsigned short*)alloc((size_t)NGEMM * KDIM * 2);
    unsigned short* Zhi = (unsigned short*)alloc((size_t)Mpad * KDIM * 2);
    unsigned short* xb  = (unsigned short*)alloc((size_t)Mpad * IN_CH * 2);
    float* ampv = (float*)alloc((size_t)N * 4);
    float* attv = (float*)alloc((size_t)N * 4);

    hipMemsetAsync(degree, 0, (size_t)N * 4, stream);

    degree_kernel<<<(E + 255) / 256, 256, 0, stream>>>(ei, degree, E);
    xcast_kernel<<<(N * IN_CH / 4 + 255) / 256, 256, 0, stream>>>(x, xb, N * IN_CH / 4);
    scan1_kernel<<<Sb, 256, 0, stream>>>(degree, part, partlog, N);
    scan2_kernel<<<1, 256, 0, stream>>>(part, partlog, logsum, Sb);
    scan3_kernel<<<Sb, 256, 0, stream>>>(degree, part, offsets, N, E);
    fill_kernel<<<(E + 255) / 256, 256, 0, stream>>>(ei, offsets, csr_src, E);
    agg_kernel<<<(Mpad * 64 + 255) / 256, 256, 0, stream>>>(xb, csr_src, offsets, degree, logsum,
                                                            Zhi, ampv, attv, N, Mpad);
    wbuild_kernel<<<(NGEMM * KDIM + 255) / 256, 256, 0, stream>>>(Wmsg, Wroot, Whi, Wlo);

    // device-capability branch (deterministic per device; capture-safe host queries)
    bool pipe = false;
    int dev = 0;
    if (hipGetDevice(&dev) == hipSuccess) {
        int optin = 0;
        if (hipDeviceGetAttribute(&optin, hipDeviceAttributeSharedMemPerBlockOptin, dev) == hipSuccess
            && optin >= (int)PIPE2_LDS_BYTES) {
            pipe = (hipFuncSetAttribute((const void*)gemm_pipe2,
                                        hipFuncAttributeMaxDynamicSharedMemorySize,
                                        PIPE2_LDS_BYTES) == hipSuccess);
        }
    }
    if (pipe) {
        dim3 ggrid(Mb2, 2);
        gemm_pipe2<<<ggrid, 512, PIPE2_LDS_BYTES, stream>>>(Zhi, Whi, Wlo, ampv, attv,
                                                            bmsg, broot, out, N);
    } else {
        dim3 ggrid(Mb, 2);
        gemm_sb<<<ggrid, 1024, 0, stream>>>(Zhi, Whi, Wlo, ampv, attv,
                                            bmsg, broot, out, N);
    }
}

// Round 5
// 258.073 us; speedup vs baseline: 1.0381x; 1.0381x over previous
//
#include <hip/hip_runtime.h>
#include <cmath>

#define IN_CH 128
#define OUT_CH 128
#define KDIM 512           // Z row: x(128) | sum(128) | mean(128) | max(128)
#define NGEMM 384          // W^T rows: permuted (colgroup, wavehalf, section, ocol16)
#define GBM 256            // gemm rows per block
#define GBN 192            // gemm cols (W^T rows) per block
#define SLOT_B 40960       // slot bytes: A 16K | Bhi 12K | Blo 12K
#define SLOT_US 20480
#define PIPE_LDS_BYTES (3 * SLOT_B)   // D=3 ring = 122880 B

typedef __attribute__((ext_vector_type(8))) short bfrag;    // 8 bf16 in 4 VGPRs
typedef __attribute__((ext_vector_type(4))) float f32x4;
typedef __attribute__((ext_vector_type(16))) float f32x16;  // 32x32 MFMA acc

// float -> bf16 round-to-nearest-even (bit pattern)
__device__ __forceinline__ unsigned short f2bf(float f) {
    unsigned int u = __float_as_uint(f);
    return (unsigned short)((u + 0x7FFFu + ((u >> 16) & 1u)) >> 16);
}
__device__ __forceinline__ float bf2f(unsigned short h) {
    return __uint_as_float(((unsigned int)h) << 16);
}
__device__ __forceinline__ float4 unpack4(uint2 u) {
    float4 r;
    r.x = __uint_as_float(u.x << 16);
    r.y = __uint_as_float(u.x & 0xFFFF0000u);
    r.z = __uint_as_float(u.y << 16);
    r.w = __uint_as_float(u.y & 0xFFFF0000u);
    return r;
}

// async 16B global->LDS (wave-level; LDS side is lane-linear base+lane*16)
__device__ __forceinline__ void gl2lds16(const void* g, void* l) {
    __builtin_amdgcn_global_load_lds(
        (const __attribute__((address_space(1))) unsigned int*)g,
        (__attribute__((address_space(3))) unsigned int*)l, 16, 0, 0);
}

// ---------------- CSR build ----------------

__global__ void degree_kernel(const int* __restrict__ ei, int* __restrict__ degree, int E) {
    int e = blockIdx.x * blockDim.x + threadIdx.x;
    if (e < E) atomicAdd(&degree[ei[E + e]], 1);
}

// ---------- device-wide exclusive scan, 3 phases ----------
__global__ __launch_bounds__(256) void scan1_kernel(const int* __restrict__ degree,
                                                    int* __restrict__ part,
                                                    float* __restrict__ partlog, int n) {
    int i = blockIdx.x * 256 + threadIdx.x;
    int d = (i < n) ? degree[i] : 0;
    float lg = (i < n) ? logf((float)d + 2.0f) : 0.f;   // == log1p(d+1)
    #pragma unroll
    for (int off = 32; off; off >>= 1) {
        d += __shfl_down(d, off);
        lg += __shfl_down(lg, off);
    }
    __shared__ int sd[4];
    __shared__ float sl[4];
    int wv = threadIdx.x >> 6;
    if ((threadIdx.x & 63) == 0) { sd[wv] = d; sl[wv] = lg; }
    __syncthreads();
    if (threadIdx.x == 0) {
        part[blockIdx.x] = (sd[0] + sd[1]) + (sd[2] + sd[3]);
        partlog[blockIdx.x] = (sl[0] + sl[1]) + (sl[2] + sl[3]);
    }
}

__global__ __launch_bounds__(256) void scan2_kernel(int* __restrict__ part,
                                                    const float* __restrict__ partlog,
                                                    float* __restrict__ logsum, int B) {
    int tid = threadIdx.x, lane = tid & 63, wv = tid >> 6;
    __shared__ int wsum[4];
    __shared__ float wl[4];
    __shared__ int carry_s;
    if (tid == 0) carry_s = 0;
    float lg = 0.f;
    __syncthreads();
    for (int base0 = 0; base0 < B; base0 += 256) {
        int idx = base0 + tid;
        int v = (idx < B) ? part[idx] : 0;
        if (idx < B) lg += partlog[idx];
        int s = v;
        #pragma unroll
        for (int off = 1; off < 64; off <<= 1) {
            int t = __shfl_up(s, off);
            if (lane >= off) s += t;
        }
        if (lane == 63) wsum[wv] = s;
        __syncthreads();
        int wbase = carry_s;
        for (int w2 = 0; w2 < wv; ++w2) wbase += wsum[w2];
        if (idx < B) part[idx] = wbase + s - v;       // exclusive prefix of block sums
        __syncthreads();
        if (tid == 0) carry_s += (wsum[0] + wsum[1]) + (wsum[2] + wsum[3]);
        __syncthreads();
    }
    #pragma unroll
    for (int off = 32; off; off >>= 1) lg += __shfl_down(lg, off);
    if (lane == 0) wl[wv] = lg;
    __syncthreads();
    if (tid == 0) logsum[0] = (wl[0] + wl[1]) + (wl[2] + wl[3]);
}

__global__ __launch_bounds__(256) void scan3_kernel(const int* __restrict__ degree,
                                                    const int* __restrict__ part,
                                                    int* __restrict__ offsets, int n, int E) {
    int i = blockIdx.x * 256 + threadIdx.x;
    int d = (i < n) ? degree[i] : 0;
    int lane = threadIdx.x & 63, wv = threadIdx.x >> 6;
    int s = d;
    #pragma unroll
    for (int off = 1; off < 64; off <<= 1) {
        int t = __shfl_up(s, off);
        if (lane >= off) s += t;
    }
    __shared__ int wsum[4];
    if (lane == 63) wsum[wv] = s;
    __syncthreads();
    int base = part[blockIdx.x];
    for (int w2 = 0; w2 < wv; ++w2) base += wsum[w2];
    if (i < n) offsets[i] = base + s - d;             // exclusive prefix
    if (i == n - 1) offsets[n] = E;                   // Σ degree == E
}

// fill bumps offsets[] in place; afterwards offsets[v] == end of v's segment.
__global__ void fill_kernel(const int* __restrict__ ei, int* __restrict__ offsets,
                            int* __restrict__ csr_src, int E) {
    int e = blockIdx.x * blockDim.x + threadIdx.x;
    if (e < E) {
        int src = ei[e];
        int dst = ei[E + e];
        int pos = atomicAdd(&offsets[dst], 1);
        csr_src[pos] = src;
    }
}

// ---------------- x -> bf16 cast (halves agg gather bytes) ----------------

__global__ void xcast_kernel(const float* __restrict__ x, unsigned short* __restrict__ xb,
                             int total4) {
    int i = blockIdx.x * 256 + threadIdx.x;    // 4 elements each
    if (i >= total4) return;
    float4 v = ((const float4*)x)[i];
    uint2 p;
    p.x = (unsigned)f2bf(v.x) | ((unsigned)f2bf(v.y) << 16);
    p.y = (unsigned)f2bf(v.z) | ((unsigned)f2bf(v.w) << 16);
    ((uint2*)xb)[i] = p;
}

// ---------------- Aggregation: one WAVE per node, bf16 edge-pair gathers ---------

__global__ __launch_bounds__(256) void agg_kernel(const unsigned short* __restrict__ xb,
                                                  const int* __restrict__ csr_src,
                                                  const int* __restrict__ offsets,
                                                  const int* __restrict__ degree,
                                                  const float* __restrict__ logsum,
                                                  unsigned short* __restrict__ Zhi,
                                                  float* __restrict__ ampv,
                                                  float* __restrict__ attv,
                                                  int N, int Mpad) {
    int node = (blockIdx.x * 256 + threadIdx.x) >> 6;
    int lane = threadIdx.x & 63;
    if (node >= Mpad) return;
    int h = lane >> 5;
    int c4 = lane & 31;
    long zbase = (long)node * KDIM + c4 * 4;
    if (node >= N) {   // pad rows: zero so GEMM reads are harmless
        if (h == 0) {
            uint2 z = make_uint2(0u, 0u);
            #pragma unroll
            for (int sec = 0; sec < 4; ++sec) *(uint2*)&Zhi[zbase + sec * 128] = z;
        }
        return;
    }
    int deg = degree[node];
    int end = offsets[node];          // post-fill end of segment
    int beg = end - deg;
    const float NEG = -3.402823466e38f;
    float4 s[4], m[4];
    #pragma unroll
    for (int u = 0; u < 4; ++u) {
        s[u] = make_float4(0.f, 0.f, 0.f, 0.f);
        m[u] = make_float4(NEG, NEG, NEG, NEG);
    }
    int i = beg;
    for (; i + 8 <= end; i += 8) {      // 4 pair-slots = 8 edges, 4 indep chains
        int idx[4];
        #pragma unroll
        for (int u = 0; u < 4; ++u) idx[u] = csr_src[i + u * 2 + h];
        uint2 raw[4];
        #pragma unroll
        for (int u = 0; u < 4; ++u) raw[u] = *(const uint2*)&xb[(long)idx[u] * IN_CH + c4 * 4];
        #pragma unroll
        for (int u = 0; u < 4; ++u) {
            float4 v = unpack4(raw[u]);
            s[u].x += v.x; s[u].y += v.y; s[u].z += v.z; s[u].w += v.w;
            m[u].x = fmaxf(m[u].x, v.x); m[u].y = fmaxf(m[u].y, v.y);
            m[u].z = fmaxf(m[u].z, v.z); m[u].w = fmaxf(m[u].w, v.w);
        }
    }
    for (; i < end; i += 2) {           // tail pairs (upper half may be inactive)
        int e = i + h;
        if (e < end) {
            float4 v = unpack4(*(const uint2*)&xb[(long)csr_src[e] * IN_CH + c4 * 4]);
            s[0].x += v.x; s[0].y += v.y; s[0].z += v.z; s[0].w += v.w;
            m[0].x = fmaxf(m[0].x, v.x); m[0].y = fmaxf(m[0].y, v.y);
            m[0].z = fmaxf(m[0].z, v.z); m[0].w = fmaxf(m[0].w, v.w);
        }
    }
    float4 sum, mx;
    sum.x = (s[0].x + s[1].x) + (s[2].x + s[3].x);
    sum.y = (s[0].y + s[1].y) + (s[2].y + s[3].y);
    sum.z = (s[0].z + s[1].z) + (s[2].z + s[3].z);
    sum.w = (s[0].w + s[1].w) + (s[2].w + s[3].w);
    mx.x = fmaxf(fmaxf(m[0].x, m[1].x), fmaxf(m[2].x, m[3].x));
    mx.y = fmaxf(fmaxf(m[0].y, m[1].y), fmaxf(m[2].y, m[3].y));
    mx.z = fmaxf(fmaxf(m[0].z, m[1].z), fmaxf(m[2].z, m[3].z));
    mx.w = fmaxf(fmaxf(m[0].w, m[1].w), fmaxf(m[2].w, m[3].w));
    // cross-half combine
    sum.x += __shfl_xor(sum.x, 32); sum.y += __shfl_xor(sum.y, 32);
    sum.z += __shfl_xor(sum.z, 32); sum.w += __shfl_xor(sum.w, 32);
    mx.x = fmaxf(mx.x, __shfl_xor(mx.x, 32)); mx.y = fmaxf(mx.y, __shfl_xor(mx.y, 32));
    mx.z = fmaxf(mx.z, __shfl_xor(mx.z, 32)); mx.w = fmaxf(mx.w, __shfl_xor(mx.w, 32));

    float inv = 1.0f / fmaxf((float)deg, 1.0f);
    float4 mean = make_float4(sum.x * inv, sum.y * inv, sum.z * inv, sum.w * inv);
    if (deg == 0) mx = make_float4(0.f, 0.f, 0.f, 0.f);
    float4 xv = unpack4(*(const uint2*)&xb[(long)node * IN_CH + c4 * 4]);

    if (h == 0) {
        float4 secs[4] = { xv, sum, mean, mx };
        #pragma unroll
        for (int sec = 0; sec < 4; ++sec) {
            float4 v = secs[sec];
            uint2 hi;
            hi.x = (unsigned)f2bf(v.x) | ((unsigned)f2bf(v.y) << 16);
            hi.y = (unsigned)f2bf(v.z) | ((unsigned)f2bf(v.w) << 16);
            *(uint2*)&Zhi[zbase + sec * 128] = hi;
        }
    }
    if (lane == 0) {
        float ref = fmaxf(logsum[0] / (float)N, 1.0f);
        float dt = log1pf((float)deg + 1.0f);
        ampv[node] = dt / ref;
        attv[node] = ref / fmaxf(dt, 1e-6f);
    }
}

// ---------------- Weight build: permuted row-major W^T, bf16 hi/lo -----------------

__global__ void wbuild_kernel(const float* __restrict__ Wmsg, const float* __restrict__ Wroot,
                              unsigned short* __restrict__ Whi, unsigned short* __restrict__ Wlo) {
    int idx = blockIdx.x * 256 + threadIdx.x;
    if (idx >= NGEMM * KDIM) return;
    int jp = idx >> 9;       // 0..383
    int k = idx & 511;
    int cg = jp / 96;
    int rem = jp - cg * 96;
    int s16 = rem >> 4;
    int r16 = rem & 15;
    int wn2 = s16 / 3;
    int sec = s16 - wn2 * 3;
    int ocol = cg * 32 + wn2 * 16 + r16;
    float v;
    if (k < 128) {
        v = (sec == 0) ? Wroot[ocol * 128 + k] : 0.f;
    } else {
        int a = (k - 128) >> 7;
        int c = (k - 128) & 127;
        v = Wmsg[ocol * 1152 + (a * 3 + sec) * 128 + c];
    }
    unsigned short h = f2bf(v);
    Whi[idx] = h;
    Wlo[idx] = f2bf(v - bf2f(h));
}

// ---------------- MFMA GEMM: 32x32x16 tiles, 8 waves, D=3 ring, counted vmcnt ------
// r5 theory: per-iter cost scales with LDS ops + MFMA instrs + waves-to-sync.
// 32x32x16 MFMA = same 16B operands, 2x FLOPs -> per block-iter: 160->128 ds_reads,
// 384->192 MFMA instrs, 16->8 waves, 48->40 stage ops. Same proven schedule:
// fire stage it+2, compute slot it%3, vmcnt(5) counted (window 2), raw s_barrier.
// Wave grid 4wm x 2wn; wave tile = 64 rows x (32 cols x 3 sections); acc 2x3xf32x16.
// LDS slot: A [0,16K): 16 groups (16 rows x K32 each, [g][q][r16][8]);
//           B [16K,40K): 24 chunks (hi 0-11, lo 12-23), [c][q][r16][8].
// 32x32x16 frag maps: A row=l&31, k=(l>>5)*8+e; B col=l&31, k same;
// C/D col=l&31, row=(reg&3)+8*(reg>>2)+4*(l>>5) (verified m74/m101).

__global__ __launch_bounds__(512, 2) void gemm_pipe32(const unsigned short* __restrict__ Zhi,
                                                      const unsigned short* __restrict__ Whi,
                                                      const unsigned short* __restrict__ Wlo,
                                                      const float* __restrict__ ampv,
                                                      const float* __restrict__ attv,
                                                      const float* __restrict__ bmsg,
                                                      const float* __restrict__ broot,
                                                      float* __restrict__ out, int M) {
    extern __shared__ char smem[];
    unsigned short* lds = (unsigned short*)smem;
    const int tid = threadIdx.x;            // 0..511
    const int w = tid >> 6;                 // 0..7
    const int lane = tid & 63;
    const int r16s = lane & 15, qs = lane >> 4;
    const int wm = w >> 1, wn = w & 1;      // wm 0..3 (64-row), wn 0..1 (96 W^T rows)
    const int row0 = blockIdx.x * GBM;
    const int cg2 = blockIdx.y;             // 0..1

    // staging: wave w -> A groups 2w,2w+1 ; B chunks 3w..3w+2 (w<4 hi, w>=4 lo)
    const unsigned short* sA0 = Zhi + (long)(row0 + (2 * w) * 16 + r16s) * KDIM + qs * 8;
    const unsigned short* sA1 = sA0 + 16 * KDIM;
    const unsigned short* Bb = (w < 4) ? Whi : Wlo;
    const int c0 = (w < 4) ? 3 * w : 3 * (w - 4);
    const unsigned short* sB0 = Bb + (long)(cg2 * GBN + c0 * 16 + r16s) * KDIM + qs * 8;
    const unsigned short* sB1 = sB0 + 16 * KDIM;
    const unsigned short* sB2 = sB0 + 32 * KDIM;
    const int dA0 = (2 * w) * 1024 + lane * 16, dA1 = dA0 + 1024;
    const int dB0 = 16384 + (3 * w) * 1024 + lane * 16;
    const int dB1 = dB0 + 1024, dB2 = dB0 + 2048;

    // prologue: stage 0 -> slot 0, stage 1 -> slot 1 (5 loads each, uniform)
    gl2lds16(sA0, smem + dA0); gl2lds16(sA1, smem + dA1);
    gl2lds16(sB0, smem + dB0); gl2lds16(sB1, smem + dB1); gl2lds16(sB2, smem + dB2);
    sA0 += 32; sA1 += 32; sB0 += 32; sB1 += 32; sB2 += 32;
    gl2lds16(sA0, smem + SLOT_B + dA0); gl2lds16(sA1, smem + SLOT_B + dA1);
    gl2lds16(sB0, smem + SLOT_B + dB0); gl2lds16(sB1, smem + SLOT_B + dB1);
    gl2lds16(sB2, smem + SLOT_B + dB2);
    sA0 += 32; sA1 += 32; sB0 += 32; sB1 += 32; sB2 += 32;

    __builtin_amdgcn_s_waitcnt(0x0F75);      // vmcnt(5): stage 0 landed
    __builtin_amdgcn_s_barrier();
    __builtin_amdgcn_sched_barrier(0);

    // read bases (ushort indices)
    const int wn2r = (lane >> 4) & 1, khr = lane >> 5, r16r = lane & 15;
    const int aBase = wm * 2048 + wn2r * 512 + khr * 128 + r16r * 8;
    const int bBase = 8192 + wn * 3072 + wn2r * 1536 + khr * 128 + r16r * 8;

    f32x16 acc[2][3] = {};

    #pragma unroll 1
    for (int it = 0; it < 16; ++it) {
        const int s = it % 3;
        if (it + 2 < 16) {                   // fire stage it+2
            char* b = smem + ((it + 2) % 3) * SLOT_B;
            gl2lds16(sA0, b + dA0); gl2lds16(sA1, b + dA1);
            gl2lds16(sB0, b + dB0); gl2lds16(sB1, b + dB1); gl2lds16(sB2, b + dB2);
            sA0 += 32; sA1 += 32; sB0 += 32; sB1 += 32; sB2 += 32;
        }
        const unsigned short* L = lds + s * SLOT_US;

        bfrag a[2][2];
        #pragma unroll
        for (int mt = 0; mt < 2; ++mt)
            #pragma unroll
            for (int kh = 0; kh < 2; ++kh)
                a[mt][kh] = *(const bfrag*)&L[aBase + mt * 1024 + kh * 256];

        #pragma unroll
        for (int kh = 0; kh < 2; ++kh) {
            #pragma unroll
            for (int p = 0; p < 2; ++p) {
                #pragma unroll
                for (int sec = 0; sec < 3; ++sec) {
                    bfrag bf = *(const bfrag*)&L[bBase + sec * 512 + kh * 256 + p * 6144];
                    acc[0][sec] = __builtin_amdgcn_mfma_f32_32x32x16_bf16(a[0][kh], bf, acc[0][sec], 0, 0, 0);
                    acc[1][sec] = __builtin_amdgcn_mfma_f32_32x32x16_bf16(a[1][kh], bf, acc[1][sec], 0, 0, 0);
                }
            }
        }

        if (it < 14)      __builtin_amdgcn_s_waitcnt(0x0F75);   // vmcnt(5): stage it+1 landed
        else if (it == 14) __builtin_amdgcn_s_waitcnt(0x0F70);  // vmcnt(0): stage 15 landed
        if (it < 15) {
            __builtin_amdgcn_s_barrier();
            __builtin_amdgcn_sched_barrier(0);
        }
    }

    // epilogue: C/D col=l&31, row=(reg&3)+8*(reg>>2)+4*(l>>5)
    const int col = (cg2 * 2 + wn) * 32 + (lane & 31);
    const float bias = bmsg[col] + broot[col];
    const int rb = row0 + wm * 64 + 4 * (lane >> 5);
    #pragma unroll
    for (int mt = 0; mt < 2; ++mt) {
        #pragma unroll
        for (int reg = 0; reg < 16; ++reg) {
            int row = rb + mt * 32 + (reg & 3) + 8 * (reg >> 2);
            if (row < M) {
                float v = acc[mt][0][reg]
                        + ampv[row] * acc[mt][1][reg]
                        + attv[row] * acc[mt][2][reg] + bias;
                out[(long)row * OUT_CH + col] = v;
            }
        }
    }
}

// ---------------- fallback: single-buffer (static 40 KB), 16-wave 16x16, barriers --

__global__ __launch_bounds__(1024, 4) void gemm_sb(const unsigned short* __restrict__ Zhi,
                                                   const unsigned short* __restrict__ Whi,
                                                   const unsigned short* __restrict__ Wlo,
                                                   const float* __restrict__ ampv,
                                                   const float* __restrict__ attv,
                                                   const float* __restrict__ bmsg,
                                                   const float* __restrict__ broot,
                                                   float* __restrict__ out, int M) {
    __shared__ unsigned short lds[SLOT_US];   // 40 KB
    const int tid = threadIdx.x;
    const int w = tid >> 6;
    const int lane = tid & 63;
    const int r16 = lane & 15, q = lane >> 4;
    const int wm = w >> 2, wn = w & 3;
    const int row0 = blockIdx.x * GBM;
    const int cg2 = blockIdx.y;

    const unsigned short* sAh = Zhi + (long)(row0 + w * 16 + r16) * KDIM + q * 8;
    const unsigned short* sB2 = (w < 12)
        ? Whi + (long)(cg2 * GBN + w * 16 + r16) * KDIM + q * 8
        : Wlo + (long)(cg2 * GBN + (w - 12) * 16 + r16) * KDIM + q * 8;
    const unsigned short* sB3 = Wlo + (long)(cg2 * GBN + (4 + w) * 16 + r16) * KDIM + q * 8;
    char* ldsb = (char*)lds;
    const int d0 = tid * 16, d2 = (1024 + tid) * 16, d3 = (2048 + tid) * 16;

    f32x4 acc[4][3] = {};
    const int jtb = (wn >> 1) * 6 + (wn & 1) * 3;

    #pragma unroll 1
    for (int it = 0; it < 16; ++it) {
        if (it) __syncthreads();
        gl2lds16(sAh, ldsb + d0); gl2lds16(sB2, ldsb + d2); if (w < 8) gl2lds16(sB3, ldsb + d3);
        sAh += 32; sB2 += 32; sB3 += 32;
        __syncthreads();

        bfrag bh[3], bl[3];
        #pragma unroll
        for (int nt = 0; nt < 3; ++nt) {
            int chb = (jtb + nt) * 512 + lane * 8;
            bh[nt] = *(const bfrag*)&lds[8192 + chb];
            bl[nt] = *(const bfrag*)&lds[14336 + chb];
        }
        #pragma unroll
        for (int mt = 0; mt < 4; ++mt) {
            bfrag ah = *(const bfrag*)&lds[((wm * 4 + mt) * 64 + lane) * 8];
            #pragma unroll
            for (int nt = 0; nt < 3; ++nt) {
                acc[mt][nt] = __builtin_amdgcn_mfma_f32_16x16x32_bf16(ah, bh[nt], acc[mt][nt], 0, 0, 0);
                acc[mt][nt] = __builtin_amdgcn_mfma_f32_16x16x32_bf16(ah, bl[nt], acc[mt][nt], 0, 0, 0);
            }
        }
    }

    const int col = (cg2 * 2 + (wn >> 1)) * 32 + (wn & 1) * 16 + r16;
    const float bias = bmsg[col] + broot[col];
    #pragma unroll
    for (int mt = 0; mt < 4; ++mt) {
        #pragma unroll
        for (int r = 0; r < 4; ++r) {
            int row = row0 + wm * 64 + mt * 16 + q * 4 + r;
            if (row < M) {
                float v = acc[mt][0][r]
                        + ampv[row] * acc[mt][1][r]
                        + attv[row] * acc[mt][2][r] + bias;
                out[(long)row * OUT_CH + col] = v;
            }
        }
    }
}

// ---------------- Launch ----------------

extern "C" void kernel_launch(void* const* d_in, const int* in_sizes, int n_in,
                              void* d_out, int out_size, void* d_ws, size_t ws_size,
                              hipStream_t stream) {
    const float* x     = (const float*)d_in[0];
    const int*   ei    = (const int*)d_in[1];
    const float* Wmsg  = (const float*)d_in[2];
    const float* bmsg  = (const float*)d_in[3];
    const float* Wroot = (const float*)d_in[4];
    const float* broot = (const float*)d_in[5];
    float* out = (float*)d_out;

    int N = in_sizes[0] / IN_CH;           // 50000
    int E = in_sizes[1] / 2;               // 600000
    int Mb = (N + GBM - 1) / GBM;          // 196
    int Mpad = Mb * GBM;                   // 50176
    int Sb = (N + 255) / 256;              // scan blocks (196)

    char* ws = (char*)d_ws;
    size_t off = 0;
    auto alloc = [&](size_t bytes) -> void* {
        void* p = ws + off;
        off = (off + bytes + 255) & ~(size_t)255;
        return p;
    };
    int* degree  = (int*)alloc((size_t)N * 4);
    int* offsets = (int*)alloc((size_t)(N + 1) * 4);
    float* logsum = (float*)alloc(4);
    int* part    = (int*)alloc((size_t)Sb * 4);
    float* partlog = (float*)alloc((size_t)Sb * 4);
    int* csr_src = (int*)alloc((size_t)E * 4);
    unsigned short* Whi = (unsigned short*)alloc((size_t)NGEMM * KDIM * 2);
    unsigned short* Wlo = (unsigned short*)alloc((size_t)NGEMM * KDIM * 2);
    unsigned short* Zhi = (unsigned short*)alloc((size_t)Mpad * KDIM * 2);
    unsigned short* xb  = (unsigned short*)alloc((size_t)Mpad * IN_CH * 2);
    float* ampv = (float*)alloc((size_t)N * 4);
    float* attv = (float*)alloc((size_t)N * 4);

    hipMemsetAsync(degree, 0, (size_t)N * 4, stream);

    degree_kernel<<<(E + 255) / 256, 256, 0, stream>>>(ei, degree, E);
    xcast_kernel<<<(N * IN_CH / 4 + 255) / 256, 256, 0, stream>>>(x, xb, N * IN_CH / 4);
    scan1_kernel<<<Sb, 256, 0, stream>>>(degree, part, partlog, N);
    scan2_kernel<<<1, 256, 0, stream>>>(part, partlog, logsum, Sb);
    scan3_kernel<<<Sb, 256, 0, stream>>>(degree, part, offsets, N, E);
    fill_kernel<<<(E + 255) / 256, 256, 0, stream>>>(ei, offsets, csr_src, E);
    agg_kernel<<<(Mpad * 64 + 255) / 256, 256, 0, stream>>>(xb, csr_src, offsets, degree, logsum,
                                                            Zhi, ampv, attv, N, Mpad);
    wbuild_kernel<<<(NGEMM * KDIM + 255) / 256, 256, 0, stream>>>(Wmsg, Wroot, Whi, Wlo);

    // device-capability branch (deterministic per device; capture-safe host queries)
    bool pipe = false;
    int dev = 0;
    if (hipGetDevice(&dev) == hipSuccess) {
        int optin = 0;
        if (hipDeviceGetAttribute(&optin, hipDeviceAttributeSharedMemPerBlockOptin, dev) == hipSuccess
            && optin >= (int)PIPE_LDS_BYTES) {
            pipe = (hipFuncSetAttribute((const void*)gemm_pipe32,
                                        hipFuncAttributeMaxDynamicSharedMemorySize,
                                        PIPE_LDS_BYTES) == hipSuccess);
        }
    }
    dim3 ggrid(Mb, 2);
    if (pipe) {
        gemm_pipe32<<<ggrid, 512, PIPE_LDS_BYTES, stream>>>(Zhi, Whi, Wlo, ampv, attv,
                                                            bmsg, broot, out, N);
    } else {
        gemm_sb<<<ggrid, 1024, 0, stream>>>(Zhi, Whi, Wlo, ampv, attv,
                                            bmsg, broot, out, N);
    }
}

// Round 6
// 242.742 us; speedup vs baseline: 1.1037x; 1.0632x over previous
//
#include <hip/hip_runtime.h>
#include <cmath>

#define IN_CH 128
#define OUT_CH 128
#define KDIM 512           // Z row: x(128) | sum(128) | mean(128) | max(128)
#define NGEMM 384          // W^T rows: permuted (colgroup, wavehalf, section, ocol16)
#define GBM 256            // gemm rows per block
#define GBN 192            // gemm cols (W^T rows) per block
#define SLOT_B 40960       // ring slot bytes: Ahi 16K | Bhi 12K | Blo 12K
#define SLOT_US 20480
#define PIPE_LDS_BYTES (3 * SLOT_B)   // D=3 ring

typedef __attribute__((ext_vector_type(8))) short bfrag;   // 8 bf16 in 4 VGPRs
typedef __attribute__((ext_vector_type(4))) float f32x4;

// float -> bf16 round-to-nearest-even (bit pattern)
__device__ __forceinline__ unsigned short f2bf(float f) {
    unsigned int u = __float_as_uint(f);
    return (unsigned short)((u + 0x7FFFu + ((u >> 16) & 1u)) >> 16);
}
__device__ __forceinline__ float bf2f(unsigned short h) {
    return __uint_as_float(((unsigned int)h) << 16);
}
__device__ __forceinline__ float4 unpack4(uint2 u) {
    float4 r;
    r.x = __uint_as_float(u.x << 16);
    r.y = __uint_as_float(u.x & 0xFFFF0000u);
    r.z = __uint_as_float(u.y << 16);
    r.w = __uint_as_float(u.y & 0xFFFF0000u);
    return r;
}

// async 16B global->LDS (wave-level; LDS side is lane-linear base+lane*16)
__device__ __forceinline__ void gl2lds16(const void* g, void* l) {
    __builtin_amdgcn_global_load_lds(
        (const __attribute__((address_space(1))) unsigned int*)g,
        (__attribute__((address_space(3))) unsigned int*)l, 16, 0, 0);
}

// ---------------- prep: degree atomics + x->bf16 cast + logsum zero (fused) --------

__global__ __launch_bounds__(256) void prep_kernel(const int* __restrict__ ei,
                                                   int* __restrict__ degree,
                                                   float* __restrict__ logsum,
                                                   const float* __restrict__ x,
                                                   unsigned short* __restrict__ xb,
                                                   int E, int total4) {
    int i = blockIdx.x * 256 + threadIdx.x;
    if (i == 0) logsum[0] = 0.f;                  // completes before scan1 (stream order)
    if (i < E) atomicAdd(&degree[ei[E + i]], 1);
    if (i < total4) {
        float4 v = ((const float4*)x)[i];
        uint2 p;
        p.x = (unsigned)f2bf(v.x) | ((unsigned)f2bf(v.y) << 16);
        p.y = (unsigned)f2bf(v.z) | ((unsigned)f2bf(v.w) << 16);
        ((uint2*)xb)[i] = p;
    }
}

// ---------- device-wide exclusive scan, 2 phases (scan2 folded away) ----------
// Phase 1: per-block (256 nodes) sums of degree; logsum via atomicAdd (order-free).
__global__ __launch_bounds__(256) void scan1_kernel(const int* __restrict__ degree,
                                                    int* __restrict__ part,
                                                    float* __restrict__ logsum, int n) {
    int i = blockIdx.x * 256 + threadIdx.x;
    int d = (i < n) ? degree[i] : 0;
    float lg = (i < n) ? logf((float)d + 2.0f) : 0.f;   // == log1p(d+1)
    #pragma unroll
    for (int off = 32; off; off >>= 1) {
        d += __shfl_down(d, off);
        lg += __shfl_down(lg, off);
    }
    __shared__ int sd[4];
    __shared__ float sl[4];
    int wv = threadIdx.x >> 6;
    if ((threadIdx.x & 63) == 0) { sd[wv] = d; sl[wv] = lg; }
    __syncthreads();
    if (threadIdx.x == 0) {
        part[blockIdx.x] = (sd[0] + sd[1]) + (sd[2] + sd[3]);
        atomicAdd(&logsum[0], (sl[0] + sl[1]) + (sl[2] + sl[3]));
    }
}

// Phase 2: each block sums part[0..b) itself (196 ints, L2-hot), then local scan.
__global__ __launch_bounds__(256) void scan3_kernel(const int* __restrict__ degree,
                                                    const int* __restrict__ part,
                                                    int* __restrict__ offsets,
                                                    int n, int E, int Sb) {
    int tid = threadIdx.x;
    int i = blockIdx.x * 256 + tid;
    int b = blockIdx.x;
    // base = sum part[0..b)
    int acc0 = 0;
    for (int j = tid; j < b; j += 256) acc0 += part[j];
    #pragma unroll
    for (int off = 32; off; off >>= 1) acc0 += __shfl_down(acc0, off);
    __shared__ int bsum[4];
    int lane = tid & 63, wv = tid >> 6;
    if (lane == 0) bsum[wv] = acc0;
    __syncthreads();
    int base = (bsum[0] + bsum[1]) + (bsum[2] + bsum[3]);

    int d = (i < n) ? degree[i] : 0;
    int s = d;
    #pragma unroll
    for (int off = 1; off < 64; off <<= 1) {
        int t = __shfl_up(s, off);
        if (lane >= off) s += t;
    }
    __shared__ int wsum[4];
    if (lane == 63) wsum[wv] = s;
    __syncthreads();
    for (int w2 = 0; w2 < wv; ++w2) base += wsum[w2];
    if (i < n) offsets[i] = base + s - d;             // exclusive prefix
    if (i == n - 1) offsets[n] = E;                   // Σ degree == E
}

// fill bumps offsets[] in place; afterwards offsets[v] == end of v's segment.
__global__ void fill_kernel(const int* __restrict__ ei, int* __restrict__ offsets,
                            int* __restrict__ csr_src, int E) {
    int e = blockIdx.x * blockDim.x + threadIdx.x;
    if (e < E) {
        int src = ei[e];
        int dst = ei[E + e];
        int pos = atomicAdd(&offsets[dst], 1);
        csr_src[pos] = src;
    }
}

// ---------------- Aggregation: one WAVE per node, bf16 edge-pair gathers ---------

__global__ __launch_bounds__(256) void agg_kernel(const unsigned short* __restrict__ xb,
                                                  const int* __restrict__ csr_src,
                                                  const int* __restrict__ offsets,
                                                  const int* __restrict__ degree,
                                                  const float* __restrict__ logsum,
                                                  unsigned short* __restrict__ Zhi,
                                                  float* __restrict__ ampv,
                                                  float* __restrict__ attv,
                                                  int N, int Mpad) {
    int node = (blockIdx.x * 256 + threadIdx.x) >> 6;
    int lane = threadIdx.x & 63;
    if (node >= Mpad) return;
    int h = lane >> 5;
    int c4 = lane & 31;
    long zbase = (long)node * KDIM + c4 * 4;
    if (node >= N) {   // pad rows: zero so GEMM reads are harmless
        if (h == 0) {
            uint2 z = make_uint2(0u, 0u);
            #pragma unroll
            for (int sec = 0; sec < 4; ++sec) *(uint2*)&Zhi[zbase + sec * 128] = z;
        }
        return;
    }
    int deg = degree[node];
    int end = offsets[node];          // post-fill end of segment
    int beg = end - deg;
    const float NEG = -3.402823466e38f;
    float4 s[4], m[4];
    #pragma unroll
    for (int u = 0; u < 4; ++u) {
        s[u] = make_float4(0.f, 0.f, 0.f, 0.f);
        m[u] = make_float4(NEG, NEG, NEG, NEG);
    }
    int i = beg;
    for (; i + 8 <= end; i += 8) {      // 4 pair-slots = 8 edges, 4 indep chains
        int idx[4];
        #pragma unroll
        for (int u = 0; u < 4; ++u) idx[u] = csr_src[i + u * 2 + h];
        uint2 raw[4];
        #pragma unroll
        for (int u = 0; u < 4; ++u) raw[u] = *(const uint2*)&xb[(long)idx[u] * IN_CH + c4 * 4];
        #pragma unroll
        for (int u = 0; u < 4; ++u) {
            float4 v = unpack4(raw[u]);
            s[u].x += v.x; s[u].y += v.y; s[u].z += v.z; s[u].w += v.w;
            m[u].x = fmaxf(m[u].x, v.x); m[u].y = fmaxf(m[u].y, v.y);
            m[u].z = fmaxf(m[u].z, v.z); m[u].w = fmaxf(m[u].w, v.w);
        }
    }
    for (; i < end; i += 2) {           // tail pairs (upper half may be inactive)
        int e = i + h;
        if (e < end) {
            float4 v = unpack4(*(const uint2*)&xb[(long)csr_src[e] * IN_CH + c4 * 4]);
            s[0].x += v.x; s[0].y += v.y; s[0].z += v.z; s[0].w += v.w;
            m[0].x = fmaxf(m[0].x, v.x); m[0].y = fmaxf(m[0].y, v.y);
            m[0].z = fmaxf(m[0].z, v.z); m[0].w = fmaxf(m[0].w, v.w);
        }
    }
    float4 sum, mx;
    sum.x = (s[0].x + s[1].x) + (s[2].x + s[3].x);
    sum.y = (s[0].y + s[1].y) + (s[2].y + s[3].y);
    sum.z = (s[0].z + s[1].z) + (s[2].z + s[3].z);
    sum.w = (s[0].w + s[1].w) + (s[2].w + s[3].w);
    mx.x = fmaxf(fmaxf(m[0].x, m[1].x), fmaxf(m[2].x, m[3].x));
    mx.y = fmaxf(fmaxf(m[0].y, m[1].y), fmaxf(m[2].y, m[3].y));
    mx.z = fmaxf(fmaxf(m[0].z, m[1].z), fmaxf(m[2].z, m[3].z));
    mx.w = fmaxf(fmaxf(m[0].w, m[1].w), fmaxf(m[2].w, m[3].w));
    // cross-half combine
    sum.x += __shfl_xor(sum.x, 32); sum.y += __shfl_xor(sum.y, 32);
    sum.z += __shfl_xor(sum.z, 32); sum.w += __shfl_xor(sum.w, 32);
    mx.x = fmaxf(mx.x, __shfl_xor(mx.x, 32)); mx.y = fmaxf(mx.y, __shfl_xor(mx.y, 32));
    mx.z = fmaxf(mx.z, __shfl_xor(mx.z, 32)); mx.w = fmaxf(mx.w, __shfl_xor(mx.w, 32));

    float inv = 1.0f / fmaxf((float)deg, 1.0f);
    float4 mean = make_float4(sum.x * inv, sum.y * inv, sum.z * inv, sum.w * inv);
    if (deg == 0) mx = make_float4(0.f, 0.f, 0.f, 0.f);
    float4 xv = unpack4(*(const uint2*)&xb[(long)node * IN_CH + c4 * 4]);

    if (h == 0) {
        float4 secs[4] = { xv, sum, mean, mx };
        #pragma unroll
        for (int sec = 0; sec < 4; ++sec) {
            float4 v = secs[sec];
            uint2 hi;
            hi.x = (unsigned)f2bf(v.x) | ((unsigned)f2bf(v.y) << 16);
            hi.y = (unsigned)f2bf(v.z) | ((unsigned)f2bf(v.w) << 16);
            *(uint2*)&Zhi[zbase + sec * 128] = hi;
        }
    }
    if (lane == 0) {
        float ref = fmaxf(logsum[0] / (float)N, 1.0f);
        float dt = log1pf((float)deg + 1.0f);
        ampv[node] = dt / ref;
        attv[node] = ref / fmaxf(dt, 1e-6f);
    }
}

// ---------------- Weight build: permuted row-major W^T, bf16 hi/lo -----------------

__global__ void wbuild_kernel(const float* __restrict__ Wmsg, const float* __restrict__ Wroot,
                              unsigned short* __restrict__ Whi, unsigned short* __restrict__ Wlo) {
    int idx = blockIdx.x * 256 + threadIdx.x;
    if (idx >= NGEMM * KDIM) return;
    int jp = idx >> 9;       // 0..383
    int k = idx & 511;
    int cg = jp / 96;
    int rem = jp - cg * 96;
    int s16 = rem >> 4;
    int r16 = rem & 15;
    int wn2 = s16 / 3;
    int sec = s16 - wn2 * 3;
    int ocol = cg * 32 + wn2 * 16 + r16;
    float v;
    if (k < 128) {
        v = (sec == 0) ? Wroot[ocol * 128 + k] : 0.f;
    } else {
        int a = (k - 128) >> 7;
        int c = (k - 128) & 127;
        v = Wmsg[ocol * 1152 + (a * 3 + sec) * 128 + c];
    }
    unsigned short h = f2bf(v);
    Whi[idx] = h;
    Wlo[idx] = f2bf(v - bf2f(h));
}

// ---------------- MFMA GEMM (r2 structure + zero-section skip) ---------------------
// 16 waves, 16x16x32, D=3 ring, counted vmcnt (window 2), raw s_barrier.
// Zero-skip: wbuild sets sections 1,2 to exact 0 for k<128 (x feeds W_root only).
// Iters 0-3 (k<128): only sec0 fragments/MFMAs (8 MFMA, 6 ds_read vs 24/10).
// Bitwise-identical accumulators; staging kept uniform so vmcnt math is unchanged.

__global__ __launch_bounds__(1024, 4) void gemm_pipe(const unsigned short* __restrict__ Zhi,
                                                     const unsigned short* __restrict__ Whi,
                                                     const unsigned short* __restrict__ Wlo,
                                                     const float* __restrict__ ampv,
                                                     const float* __restrict__ attv,
                                                     const float* __restrict__ bmsg,
                                                     const float* __restrict__ broot,
                                                     float* __restrict__ out, int M) {
    extern __shared__ char smem[];
    unsigned short* lds = (unsigned short*)smem;
    const int tid = threadIdx.x;
    const int w = tid >> 6;                 // 0..15
    const int lane = tid & 63;
    const int r16 = lane & 15, q = lane >> 4;
    const int wm = w >> 2, wn = w & 3;
    const int row0 = blockIdx.x * GBM;
    const int cg2 = blockIdx.y;             // 0..1

    const unsigned short* sAh = Zhi + (long)(row0 + w * 16 + r16) * KDIM + q * 8;
    const unsigned short* sB2 = (w < 12)
        ? Whi + (long)(cg2 * GBN + w * 16 + r16) * KDIM + q * 8
        : Wlo + (long)(cg2 * GBN + (w - 12) * 16 + r16) * KDIM + q * 8;
    const unsigned short* sB3 = Wlo + (long)(cg2 * GBN + (4 + w) * 16 + r16) * KDIM + q * 8;
    const int d0 = tid * 16, d2 = (1024 + tid) * 16, d3 = (2048 + tid) * 16;

    // prologue: stage 0 -> slot 0, stage 1 -> slot 1
    gl2lds16(sAh, smem + d0); gl2lds16(sB2, smem + d2); if (w < 8) gl2lds16(sB3, smem + d3);
    sAh += 32; sB2 += 32; sB3 += 32;
    gl2lds16(sAh, smem + SLOT_B + d0); gl2lds16(sB2, smem + SLOT_B + d2);
    if (w < 8) gl2lds16(sB3, smem + SLOT_B + d3);
    sAh += 32; sB2 += 32; sB3 += 32;

    // stage 0 landed (own): outstanding 2L -> wait to L
    if (w < 8) __builtin_amdgcn_s_waitcnt(0x0F73);      // vmcnt(3)
    else       __builtin_amdgcn_s_waitcnt(0x0F72);      // vmcnt(2)
    __builtin_amdgcn_s_barrier();
    __builtin_amdgcn_sched_barrier(0);

    f32x4 acc[4][3] = {};
    const int jtb = (wn >> 1) * 6 + (wn & 1) * 3;

    // ---- iters 0..3: k<128, sections 1,2 are exact zeros -> sec0 only ----
    #pragma unroll 1
    for (int it = 0; it < 4; ++it) {
        const int s = it % 3;
        {                                                // fire stage it+2 (< 16)
            char* b = smem + ((it + 2) % 3) * SLOT_B;
            gl2lds16(sAh, b + d0); gl2lds16(sB2, b + d2); if (w < 8) gl2lds16(sB3, b + d3);
            sAh += 32; sB2 += 32; sB3 += 32;
        }
        const unsigned short* L = lds + s * SLOT_US;

        int chb = jtb * 512 + lane * 8;
        bfrag bh0 = *(const bfrag*)&L[8192 + chb];
        bfrag bl0 = *(const bfrag*)&L[14336 + chb];
        #pragma unroll
        for (int mt = 0; mt < 4; ++mt) {
            bfrag ah = *(const bfrag*)&L[((wm * 4 + mt) * 64 + lane) * 8];
            acc[mt][0] = __builtin_amdgcn_mfma_f32_16x16x32_bf16(ah, bh0, acc[mt][0], 0, 0, 0);
            acc[mt][0] = __builtin_amdgcn_mfma_f32_16x16x32_bf16(ah, bl0, acc[mt][0], 0, 0, 0);
        }

        if (w < 8) __builtin_amdgcn_s_waitcnt(0x0F73);   // own stage(it+1) landed
        else       __builtin_amdgcn_s_waitcnt(0x0F72);
        __builtin_amdgcn_s_barrier();
        __builtin_amdgcn_sched_barrier(0);
    }

    // ---- iters 4..15: full 3-section body ----
    #pragma unroll 1
    for (int it = 4; it < 16; ++it) {
        const int s = it % 3;
        if (it + 2 < 16) {                               // fire stage it+2
            char* b = smem + ((it + 2) % 3) * SLOT_B;
            gl2lds16(sAh, b + d0); gl2lds16(sB2, b + d2); if (w < 8) gl2lds16(sB3, b + d3);
            sAh += 32; sB2 += 32; sB3 += 32;
        }
        const unsigned short* L = lds + s * SLOT_US;

        bfrag bh[3], bl[3];
        #pragma unroll
        for (int nt = 0; nt < 3; ++nt) {
            int chb = (jtb + nt) * 512 + lane * 8;
            bh[nt] = *(const bfrag*)&L[8192 + chb];
            bl[nt] = *(const bfrag*)&L[14336 + chb];
        }
        #pragma unroll
        for (int mt = 0; mt < 4; ++mt) {
            bfrag ah = *(const bfrag*)&L[((wm * 4 + mt) * 64 + lane) * 8];
            #pragma unroll
            for (int nt = 0; nt < 3; ++nt) {
                acc[mt][nt] = __builtin_amdgcn_mfma_f32_16x16x32_bf16(ah, bh[nt], acc[mt][nt], 0, 0, 0);
                acc[mt][nt] = __builtin_amdgcn_mfma_f32_16x16x32_bf16(ah, bl[nt], acc[mt][nt], 0, 0, 0);
            }
        }

        if (it < 14) {                                   // own stage(it+1) landed
            if (w < 8) __builtin_amdgcn_s_waitcnt(0x0F73);
            else       __builtin_amdgcn_s_waitcnt(0x0F72);
        } else if (it == 14) {
            __builtin_amdgcn_s_waitcnt(0x0F70);          // vmcnt(0): stage 15 landed
        }
        if (it < 15) {
            __builtin_amdgcn_s_barrier();
            __builtin_amdgcn_sched_barrier(0);
        }
    }

    // fused epilogue: C/D layout col=lane&15, row=q*4+r (verified m89/m91)
    const int col = (cg2 * 2 + (wn >> 1)) * 32 + (wn & 1) * 16 + r16;
    const float bias = bmsg[col] + broot[col];
    #pragma unroll
    for (int mt = 0; mt < 4; ++mt) {
        #pragma unroll
        for (int r = 0; r < 4; ++r) {
            int row = row0 + wm * 64 + mt * 16 + q * 4 + r;
            if (row < M) {
                float v = acc[mt][0][r]
                        + ampv[row] * acc[mt][1][r]
                        + attv[row] * acc[mt][2][r] + bias;
                out[(long)row * OUT_CH + col] = v;
            }
        }
    }
}

// ---------------- fallback: single-buffer (static 40 KB), barriers -----------------

__global__ __launch_bounds__(1024, 4) void gemm_sb(const unsigned short* __restrict__ Zhi,
                                                   const unsigned short* __restrict__ Whi,
                                                   const unsigned short* __restrict__ Wlo,
                                                   const float* __restrict__ ampv,
                                                   const float* __restrict__ attv,
                                                   const float* __restrict__ bmsg,
                                                   const float* __restrict__ broot,
                                                   float* __restrict__ out, int M) {
    __shared__ unsigned short lds[SLOT_US];   // 40 KB
    const int tid = threadIdx.x;
    const int w = tid >> 6;
    const int lane = tid & 63;
    const int r16 = lane & 15, q = lane >> 4;
    const int wm = w >> 2, wn = w & 3;
    const int row0 = blockIdx.x * GBM;
    const int cg2 = blockIdx.y;

    const unsigned short* sAh = Zhi + (long)(row0 + w * 16 + r16) * KDIM + q * 8;
    const unsigned short* sB2 = (w < 12)
        ? Whi + (long)(cg2 * GBN + w * 16 + r16) * KDIM + q * 8
        : Wlo + (long)(cg2 * GBN + (w - 12) * 16 + r16) * KDIM + q * 8;
    const unsigned short* sB3 = Wlo + (long)(cg2 * GBN + (4 + w) * 16 + r16) * KDIM + q * 8;
    char* ldsb = (char*)lds;
    const int d0 = tid * 16, d2 = (1024 + tid) * 16, d3 = (2048 + tid) * 16;

    f32x4 acc[4][3] = {};
    const int jtb = (wn >> 1) * 6 + (wn & 1) * 3;

    #pragma unroll 1
    for (int it = 0; it < 16; ++it) {
        if (it) __syncthreads();
        gl2lds16(sAh, ldsb + d0); gl2lds16(sB2, ldsb + d2); if (w < 8) gl2lds16(sB3, ldsb + d3);
        sAh += 32; sB2 += 32; sB3 += 32;
        __syncthreads();

        bfrag bh[3], bl[3];
        #pragma unroll
        for (int nt = 0; nt < 3; ++nt) {
            int chb = (jtb + nt) * 512 + lane * 8;
            bh[nt] = *(const bfrag*)&lds[8192 + chb];
            bl[nt] = *(const bfrag*)&lds[14336 + chb];
        }
        #pragma unroll
        for (int mt = 0; mt < 4; ++mt) {
            bfrag ah = *(const bfrag*)&lds[((wm * 4 + mt) * 64 + lane) * 8];
            #pragma unroll
            for (int nt = 0; nt < 3; ++nt) {
                acc[mt][nt] = __builtin_amdgcn_mfma_f32_16x16x32_bf16(ah, bh[nt], acc[mt][nt], 0, 0, 0);
                acc[mt][nt] = __builtin_amdgcn_mfma_f32_16x16x32_bf16(ah, bl[nt], acc[mt][nt], 0, 0, 0);
            }
        }
    }

    const int col = (cg2 * 2 + (wn >> 1)) * 32 + (wn & 1) * 16 + r16;
    const float bias = bmsg[col] + broot[col];
    #pragma unroll
    for (int mt = 0; mt < 4; ++mt) {
        #pragma unroll
        for (int r = 0; r < 4; ++r) {
            int row = row0 + wm * 64 + mt * 16 + q * 4 + r;
            if (row < M) {
                float v = acc[mt][0][r]
                        + ampv[row] * acc[mt][1][r]
                        + attv[row] * acc[mt][2][r] + bias;
                out[(long)row * OUT_CH + col] = v;
            }
        }
    }
}

// ---------------- Launch ----------------

extern "C" void kernel_launch(void* const* d_in, const int* in_sizes, int n_in,
                              void* d_out, int out_size, void* d_ws, size_t ws_size,
                              hipStream_t stream) {
    const float* x     = (const float*)d_in[0];
    const int*   ei    = (const int*)d_in[1];
    const float* Wmsg  = (const float*)d_in[2];
    const float* bmsg  = (const float*)d_in[3];
    const float* Wroot = (const float*)d_in[4];
    const float* broot = (const float*)d_in[5];
    float* out = (float*)d_out;

    int N = in_sizes[0] / IN_CH;           // 50000
    int E = in_sizes[1] / 2;               // 600000
    int Mb = (N + GBM - 1) / GBM;          // 196
    int Mpad = Mb * GBM;                   // 50176
    int Sb = (N + 255) / 256;              // scan blocks (196)
    int total4 = N * IN_CH / 4;            // 1.6M quads

    char* ws = (char*)d_ws;
    size_t off = 0;
    auto alloc = [&](size_t bytes) -> void* {
        void* p = ws + off;
        off = (off + bytes + 255) & ~(size_t)255;
        return p;
    };
    int* degree  = (int*)alloc((size_t)N * 4);
    int* offsets = (int*)alloc((size_t)(N + 1) * 4);
    float* logsum = (float*)alloc(4);
    int* part    = (int*)alloc((size_t)Sb * 4);
    int* csr_src = (int*)alloc((size_t)E * 4);
    unsigned short* Whi = (unsigned short*)alloc((size_t)NGEMM * KDIM * 2);
    unsigned short* Wlo = (unsigned short*)alloc((size_t)NGEMM * KDIM * 2);
    unsigned short* Zhi = (unsigned short*)alloc((size_t)Mpad * KDIM * 2);
    unsigned short* xb  = (unsigned short*)alloc((size_t)Mpad * IN_CH * 2);
    float* ampv = (float*)alloc((size_t)N * 4);
    float* attv = (float*)alloc((size_t)N * 4);

    hipMemsetAsync(degree, 0, (size_t)N * 4, stream);

    int prepg = (max(E, total4) + 255) / 256;
    prep_kernel<<<prepg, 256, 0, stream>>>(ei, degree, logsum, x, xb, E, total4);
    scan1_kernel<<<Sb, 256, 0, stream>>>(degree, part, logsum, N);
    scan3_kernel<<<Sb, 256, 0, stream>>>(degree, part, offsets, N, E, Sb);
    fill_kernel<<<(E + 255) / 256, 256, 0, stream>>>(ei, offsets, csr_src, E);
    agg_kernel<<<(Mpad * 64 + 255) / 256, 256, 0, stream>>>(xb, csr_src, offsets, degree, logsum,
                                                            Zhi, ampv, attv, N, Mpad);
    wbuild_kernel<<<(NGEMM * KDIM + 255) / 256, 256, 0, stream>>>(Wmsg, Wroot, Whi, Wlo);

    // device-capability branch (deterministic per device; capture-safe host queries)
    bool pipe = false;
    int dev = 0;
    if (hipGetDevice(&dev) == hipSuccess) {
        int optin = 0;
        if (hipDeviceGetAttribute(&optin, hipDeviceAttributeSharedMemPerBlockOptin, dev) == hipSuccess
            && optin >= (int)PIPE_LDS_BYTES) {
            pipe = (hipFuncSetAttribute((const void*)gemm_pipe,
                                        hipFuncAttributeMaxDynamicSharedMemorySize,
                                        PIPE_LDS_BYTES) == hipSuccess);
        }
    }
    dim3 ggrid(Mb, 2);
    if (pipe) {
        gemm_pipe<<<ggrid, 1024, PIPE_LDS_BYTES, stream>>>(Zhi, Whi, Wlo, ampv, attv,
                                                           bmsg, broot, out, N);
    } else {
        gemm_sb<<<ggrid, 1024, 0, stream>>>(Zhi, Whi, Wlo, ampv, attv,
                                            bmsg, broot, out, N);
    }
}